// Round 1
// baseline (738.087 us; speedup 1.0000x reference)
//
#include <hip/hip_runtime.h>
#include <hip/hip_bf16.h>

// Problem constants
#define B_   128
#define J_   2048
#define P_   8
#define N_   32
#define D_   16

#define KC   64     // K-split chunks over j for the s-step kernel
#define JPB  32     // j's per A-block (J_/KC)
#define SUBJ 4      // j's per LDS sub-chunk in A

// ---------------------------------------------------------------------------
// Z: zero the s accumulator (65536 floats)
// ---------------------------------------------------------------------------
__global__ __launch_bounds__(256) void capsZ(float* __restrict__ s) {
    int gid = blockIdx.x * 256 + threadIdx.x;
    s[gid] = 0.0f;
}

// ---------------------------------------------------------------------------
// A: s[b,n,d] (+)= sum_j c[b,n,j] * sum_p W[n,j,d,p]*x[b,j,p]
//    mode 0: c = 1/32 (iteration 0);  mode 1: c = softmax(blog) via md
//    grid: 32 n * 64 kc = 2048 blocks, 256 threads
//    atomicAdd partial results into s (s must be zeroed beforehand)
// ---------------------------------------------------------------------------
__global__ __launch_bounds__(256) void capsA(const float* __restrict__ W,
                                             const float* __restrict__ x,
                                             const float* __restrict__ blog,
                                             const float2* __restrict__ md,
                                             float* __restrict__ s,
                                             int mode) {
    __shared__ float c_lds[B_ * (JPB + 1)];        // [128][33]  16.9 KB
    __shared__ float w_lds[SUBJ * 128];            // [4][16][8]  2 KB
    __shared__ float x_lds[SUBJ * P_ * 132];       // [32][132]  16.9 KB (transposed x)

    const int t  = threadIdx.x;
    const int n  = blockIdx.x & 31;
    const int kc = blockIdx.x >> 5;
    const int j0 = kc * JPB;

    // ---- stage c for this block's 32-j window, all 128 b (coalesced) ----
    for (int idx = t; idx < B_ * JPB; idx += 256) {
        int b  = idx >> 5;
        int jj = idx & 31;
        float c;
        if (mode == 0) {
            c = 1.0f / 32.0f;
        } else {
            float  lg  = blog[(b * N_ + n) * J_ + j0 + jj];
            float2 mdv = md[b * J_ + j0 + jj];
            c = __expf(lg - mdv.x) * mdv.y;
        }
        c_lds[b * (JPB + 1) + jj] = c;
    }

    const int dg = t >> 5;   // 0..7  -> d = 2dg, 2dg+1
    const int bg = t & 31;   // 0..31 -> b = bg*4 .. bg*4+3

    float acc[2][4] = {{0.f,0.f,0.f,0.f},{0.f,0.f,0.f,0.f}};

    for (int jc = 0; jc < JPB; jc += SUBJ) {
        __syncthreads();   // c visible (1st iter); prior reads done before overwrite
        // stage W sub-chunk: 4 j * 128 floats, contiguous
        for (int idx = t; idx < SUBJ * 128; idx += 256)
            w_lds[idx] = W[(n * J_ + j0 + jc) * 128 + idx];
        // stage x transposed: dest [r=jj*8+p][b], src contiguous 32-float runs per b
        for (int idx = t; idx < SUBJ * P_ * B_; idx += 256) {
            int b = idx >> 5;
            int r = idx & 31;
            x_lds[r * 132 + b] = x[b * (J_ * P_) + (j0 + jc) * P_ + r];
        }
        __syncthreads();

        #pragma unroll
        for (int jj = 0; jj < SUBJ; ++jj) {
            float tmp[2][4] = {{0.f,0.f,0.f,0.f},{0.f,0.f,0.f,0.f}};
            #pragma unroll
            for (int p = 0; p < P_; ++p) {
                const float4 xv = *(const float4*)&x_lds[(jj * 8 + p) * 132 + bg * 4];
                float w0 = w_lds[jj * 128 + (2 * dg)     * 8 + p];
                float w1 = w_lds[jj * 128 + (2 * dg + 1) * 8 + p];
                tmp[0][0] += w0 * xv.x; tmp[0][1] += w0 * xv.y;
                tmp[0][2] += w0 * xv.z; tmp[0][3] += w0 * xv.w;
                tmp[1][0] += w1 * xv.x; tmp[1][1] += w1 * xv.y;
                tmp[1][2] += w1 * xv.z; tmp[1][3] += w1 * xv.w;
            }
            #pragma unroll
            for (int bb = 0; bb < 4; ++bb) {
                float cv = c_lds[(bg * 4 + bb) * (JPB + 1) + jc + jj];
                acc[0][bb] += cv * tmp[0][bb];
                acc[1][bb] += cv * tmp[1][bb];
            }
        }
    }

    #pragma unroll
    for (int dd = 0; dd < 2; ++dd)
        #pragma unroll
        for (int bb = 0; bb < 4; ++bb) {
            int b = bg * 4 + bb;
            int d = 2 * dg + dd;
            atomicAdd(&s[b * (N_ * D_) + n * D_ + d], acc[dd][bb]);
        }
}

// ---------------------------------------------------------------------------
// R: out[b,n,d] = squash(s + bias)   (16-lane shfl reduce for ||s||^2)
//    grid: 256 blocks * 256 threads = 65536
// ---------------------------------------------------------------------------
__global__ __launch_bounds__(256) void capsR(const float* __restrict__ s,
                                             const float* __restrict__ bias,
                                             float* __restrict__ out) {
    int gid = blockIdx.x * 256 + threadIdx.x;
    int nd  = gid & 511;                 // n*16+d
    float sv = s[gid] + bias[nd];
    float sq = sv * sv;
    sq += __shfl_xor(sq, 1);
    sq += __shfl_xor(sq, 2);
    sq += __shfl_xor(sq, 4);
    sq += __shfl_xor(sq, 8);
    float scale = sq / (1.0f + sq) / sqrtf(sq + 1e-7f);
    out[gid] = scale * sv;
}

// ---------------------------------------------------------------------------
// B: blog[b,n,j] (+)= sum_p x[b,j,p] * (sum_d o[b,n,d]*W[n,j,d,p])
//    W slice held in 16 VGPRs per thread (read once, 32 MB total).
//    grid: 32 n * 64 jt = 2048 blocks, 256 threads (32 j * 8 p)
// ---------------------------------------------------------------------------
__global__ __launch_bounds__(256) void capsB(const float* __restrict__ W,
                                             const float* __restrict__ x,
                                             const float* __restrict__ o,
                                             float* __restrict__ blog,
                                             int accumulate) {
    __shared__ float o_lds[B_ * D_];     // 8 KB: o[:, n, :]
    const int t  = threadIdx.x;
    const int n  = blockIdx.x & 31;
    const int jt = blockIdx.x >> 5;
    const int j0 = jt * 32;
    const int jl = t >> 3;               // 0..31
    const int q  = t & 7;                // p index
    const int j  = j0 + jl;

    float wreg[16];
    #pragma unroll
    for (int d = 0; d < 16; ++d)
        wreg[d] = W[((n * J_ + j) * 16 + d) * 8 + q];

    for (int idx = t; idx < B_ * D_; idx += 256) {
        int b  = idx >> 4;
        int dd = idx & 15;
        o_lds[idx] = o[(b * N_ + n) * D_ + dd];
    }
    __syncthreads();

    for (int b = 0; b < B_; ++b) {
        const float4* op = (const float4*)&o_lds[b * 16];
        float4 o0 = op[0], o1 = op[1], o2 = op[2], o3 = op[3];
        float dot = o0.x * wreg[0]  + o0.y * wreg[1]  + o0.z * wreg[2]  + o0.w * wreg[3]
                  + o1.x * wreg[4]  + o1.y * wreg[5]  + o1.z * wreg[6]  + o1.w * wreg[7]
                  + o2.x * wreg[8]  + o2.y * wreg[9]  + o2.z * wreg[10] + o2.w * wreg[11]
                  + o3.x * wreg[12] + o3.y * wreg[13] + o3.z * wreg[14] + o3.w * wreg[15];
        float xv = x[(b * J_ + j) * P_ + q];
        float tt = dot * xv;
        tt += __shfl_xor(tt, 1);
        tt += __shfl_xor(tt, 2);
        tt += __shfl_xor(tt, 4);
        if (q == 0) {
            int addr = (b * N_ + n) * J_ + j;
            blog[addr] = accumulate ? (blog[addr] + tt) : tt;
        }
    }
}

// ---------------------------------------------------------------------------
// D: per (b,j): m = max_n blog, invd = 1/sum_n exp(blog-m); also zero s
//    grid: 1024 blocks * 256 = 262144 threads
// ---------------------------------------------------------------------------
__global__ __launch_bounds__(256) void capsD(const float* __restrict__ blog,
                                             float2* __restrict__ md,
                                             float* __restrict__ s) {
    int gid = blockIdx.x * 256 + threadIdx.x;
    if (gid < B_ * N_ * D_) s[gid] = 0.0f;   // fused zero of s for next A
    int b = gid >> 11;
    int j = gid & 2047;
    float v[32];
    float m = -1e30f;
    #pragma unroll
    for (int n = 0; n < 32; ++n) {
        v[n] = blog[(b * N_ + n) * J_ + j];
        m = fmaxf(m, v[n]);
    }
    float sum = 0.0f;
    #pragma unroll
    for (int n = 0; n < 32; ++n) sum += __expf(v[n] - m);
    md[gid] = make_float2(m, 1.0f / sum);
}

// ---------------------------------------------------------------------------
extern "C" void kernel_launch(void* const* d_in, const int* in_sizes, int n_in,
                              void* d_out, int out_size, void* d_ws, size_t ws_size,
                              hipStream_t stream) {
    const float* x    = (const float*)d_in[0];   // [128,2048,8]
    const float* W    = (const float*)d_in[1];   // [32,2048,16,8]
    const float* bias = (const float*)d_in[2];   // [32,16]
    float* out = (float*)d_out;                  // [128,32,16]

    float*  ws   = (float*)d_ws;
    float*  blog = ws;                               // 8,388,608 floats (32 MB)
    float2* md   = (float2*)(ws + (size_t)B_ * N_ * J_);      // 262,144 float2 (2 MB)
    float*  s    = ws + (size_t)B_ * N_ * J_ + 2 * (size_t)B_ * J_;  // 65,536 floats

    dim3 blk(256);

    // ---- routing iteration 0 (c uniform) ----
    capsZ<<<dim3(B_ * N_ * D_ / 256), blk, 0, stream>>>(s);
    capsA<<<dim3(N_ * KC), blk, 0, stream>>>(W, x, blog, md, s, 0);
    capsR<<<dim3(B_ * N_ * D_ / 256), blk, 0, stream>>>(s, bias, out);
    capsB<<<dim3(N_ * (J_ / 32)), blk, 0, stream>>>(W, x, out, blog, 0);

    // ---- routing iteration 1 ----
    capsD<<<dim3(B_ * J_ / 256), blk, 0, stream>>>(blog, md, s);
    capsA<<<dim3(N_ * KC), blk, 0, stream>>>(W, x, blog, md, s, 1);
    capsR<<<dim3(B_ * N_ * D_ / 256), blk, 0, stream>>>(s, bias, out);
    capsB<<<dim3(N_ * (J_ / 32)), blk, 0, stream>>>(W, x, out, blog, 1);

    // ---- routing iteration 2 (final) ----
    capsD<<<dim3(B_ * J_ / 256), blk, 0, stream>>>(blog, md, s);
    capsA<<<dim3(N_ * KC), blk, 0, stream>>>(W, x, blog, md, s, 1);
    capsR<<<dim3(B_ * N_ * D_ / 256), blk, 0, stream>>>(s, bias, out);
}